// Round 2
// baseline (315.705 us; speedup 1.0000x reference)
//
#include <hip/hip_runtime.h>
#include <hip/hip_bf16.h>

typedef __attribute__((ext_vector_type(4))) float  f32x4;
typedef __attribute__((ext_vector_type(8))) _Float16 h16x8;

#define EMB 128
#define NSEQ 4096
#define NB 8

// ---------------- prep: hi/lo split transposed weights ----------------
// whiT[widx][e][d] = hi((f16) w[d][e]), wloT = residual
__global__ void prep_w(const float* __restrict__ wq, const float* __restrict__ wk,
                       const float* __restrict__ wv, _Float16* __restrict__ whiT,
                       _Float16* __restrict__ wloT) {
    int idx = blockIdx.x * 256 + threadIdx.x;          // 3*128*128 = 49152
    if (idx >= 3 * EMB * EMB) return;
    int widx = idx >> 14;
    int rem  = idx & 16383;
    int d = rem >> 7;
    int e = rem & 127;
    const float* w = (widx == 0) ? wq : (widx == 1) ? wk : wv;
    float v = w[d * 128 + e];
    _Float16 hi = (_Float16)v;
    _Float16 lo = (_Float16)(v - (float)hi);
    whiT[(size_t)widx * 16384 + (size_t)e * 128 + d] = hi;
    wloT[(size_t)widx * 16384 + (size_t)e * 128 + d] = lo;
}

// ---------------- QKV projection (hi/lo split, fp32-accurate) ----------------
// q,k layout: [token][256]: [0:128]=hi f16, [128:256]=lo f16.  vT: [b][e][n] f16.
__global__ __launch_bounds__(256) void qkv_proj(const float* __restrict__ x,
                                                const _Float16* __restrict__ whiT,
                                                const _Float16* __restrict__ wloT,
                                                _Float16* __restrict__ q,
                                                _Float16* __restrict__ k,
                                                _Float16* __restrict__ vT) {
    const int lane = threadIdx.x & 63;
    const int wave = threadIdx.x >> 6;
    const int g    = lane >> 4;
    const int lr   = lane & 15;
    const int rb   = blockIdx.x * 64 + wave * 16;

    h16x8 xhi[4], xlo[4];
    {
        const float* xrow = x + (size_t)(rb + lr) * EMB;
        #pragma unroll
        for (int kc = 0; kc < 4; ++kc) {
            const float* p = xrow + kc * 32 + g * 8;
            h16x8 ah, al;
            #pragma unroll
            for (int j = 0; j < 8; ++j) {
                float v = p[j];
                _Float16 h = (_Float16)v;
                ah[j] = h;
                al[j] = (_Float16)(v - (float)h);
            }
            xhi[kc] = ah; xlo[kc] = al;
        }
    }

    const int b  = rb >> 12;
    const int n0 = rb & 4095;

    for (int widx = 0; widx < 3; ++widx) {
        f32x4 acc[8];
        #pragma unroll
        for (int ct = 0; ct < 8; ++ct) acc[ct] = (f32x4){0.f, 0.f, 0.f, 0.f};

        const _Float16* wh = whiT + (size_t)widx * 16384;
        const _Float16* wl = wloT + (size_t)widx * 16384;
        #pragma unroll
        for (int kc = 0; kc < 4; ++kc) {
            #pragma unroll
            for (int ct = 0; ct < 8; ++ct) {
                size_t off = (size_t)(ct * 16 + lr) * 128 + kc * 32 + g * 8;
                h16x8 bh = *(const h16x8*)(wh + off);
                h16x8 bl = *(const h16x8*)(wl + off);
                acc[ct] = __builtin_amdgcn_mfma_f32_16x16x32_f16(xhi[kc], bh, acc[ct], 0, 0, 0);
                acc[ct] = __builtin_amdgcn_mfma_f32_16x16x32_f16(xlo[kc], bh, acc[ct], 0, 0, 0);
                acc[ct] = __builtin_amdgcn_mfma_f32_16x16x32_f16(xhi[kc], bl, acc[ct], 0, 0, 0);
            }
        }

        if (widx < 2) {
            _Float16* out = (widx == 0) ? q : k;
            #pragma unroll
            for (int ct = 0; ct < 8; ++ct)
                #pragma unroll
                for (int r = 0; r < 4; ++r) {
                    size_t row = rb + g * 4 + r;
                    float v = acc[ct][r];
                    _Float16 h = (_Float16)v;
                    out[row * 256 + ct * 16 + lr]       = h;
                    out[row * 256 + 128 + ct * 16 + lr] = (_Float16)(v - (float)h);
                }
        } else {
            #pragma unroll
            for (int ct = 0; ct < 8; ++ct)
                #pragma unroll
                for (int r = 0; r < 4; ++r) {
                    int e  = ct * 16 + lr;
                    int nn = n0 + g * 4 + r;
                    vT[((size_t)b * EMB + e) * NSEQ + nn] = (_Float16)acc[ct][r];
                }
        }
    }
}

// ---------------- flash attention ----------------
#define SKS 264   // K tile row stride (f16): 64 rows x 256 (hi|lo), pad 8
#define SVS 72    // Vt tile row stride: 128 rows x 64, pad 8
#define SPS 72    // P tile row stride: 16 rows x 64, pad 8

__global__ __launch_bounds__(256) void flash(const _Float16* __restrict__ q,
                                             const _Float16* __restrict__ k,
                                             const _Float16* __restrict__ vT,
                                             float* __restrict__ out) {
    __shared__ _Float16 Ks[64 * SKS];
    __shared__ _Float16 Vs[128 * SVS];
    __shared__ _Float16 Ps[4][16 * SPS];

    const int lane = threadIdx.x & 63;
    const int wave = threadIdx.x >> 6;
    const int g    = lane >> 4;
    const int lr   = lane & 15;
    const int b    = blockIdx.x >> 6;
    const int qt   = blockIdx.x & 63;
    const size_t qtok = (size_t)b * NSEQ + qt * 64 + wave * 16;

    // Q fragments hi/lo (stay in regs)
    h16x8 qhi[4], qlo[4];
    #pragma unroll
    for (int kc = 0; kc < 4; ++kc) {
        const _Float16* p = q + (qtok + lr) * 256 + kc * 32 + g * 8;
        qhi[kc] = *(const h16x8*)(p);
        qlo[kc] = *(const h16x8*)(p + 128);
    }

    f32x4 o[8];
    #pragma unroll
    for (int ct = 0; ct < 8; ++ct) o[ct] = (f32x4){0.f, 0.f, 0.f, 0.f};
    float m[4] = {-1e30f, -1e30f, -1e30f, -1e30f};
    float l[4] = {0.f, 0.f, 0.f, 0.f};
    const float scale = 0.08838834764831845f;   // 1/sqrt(128)

    for (int t = 0; t < NSEQ / 64; ++t) {
        const int kvbase = t * 64;
        __syncthreads();
        // stage K tile: 64 rows x 256 f16 (hi|lo)
        {
            int r = threadIdx.x >> 2, c0 = (threadIdx.x & 3) * 64;
            const _Float16* src = k + ((size_t)b * NSEQ + kvbase + r) * 256 + c0;
            _Float16* dst = &Ks[r * SKS + c0];
            #pragma unroll
            for (int i = 0; i < 8; ++i) *(h16x8*)(dst + i * 8) = *(const h16x8*)(src + i * 8);
        }
        // stage Vt tile: 128 rows x 64 f16
        {
            int r = threadIdx.x >> 1, c0 = (threadIdx.x & 1) * 32;
            const _Float16* src = vT + ((size_t)b * EMB + r) * NSEQ + kvbase + c0;
            _Float16* dst = &Vs[r * SVS + c0];
            #pragma unroll
            for (int i = 0; i < 4; ++i) *(h16x8*)(dst + i * 8) = *(const h16x8*)(src + i * 8);
        }
        __syncthreads();

        // S = Q K^T * scale, hi/lo 3-term
        f32x4 s[4];
        #pragma unroll
        for (int ct = 0; ct < 4; ++ct) {
            f32x4 acc = (f32x4){0.f, 0.f, 0.f, 0.f};
            #pragma unroll
            for (int kc = 0; kc < 4; ++kc) {
                const _Float16* kp = &Ks[(ct * 16 + lr) * SKS + kc * 32 + g * 8];
                h16x8 kh = *(const h16x8*)(kp);
                h16x8 kl = *(const h16x8*)(kp + 128);
                acc = __builtin_amdgcn_mfma_f32_16x16x32_f16(qhi[kc], kh, acc, 0, 0, 0);
                acc = __builtin_amdgcn_mfma_f32_16x16x32_f16(qlo[kc], kh, acc, 0, 0, 0);
                acc = __builtin_amdgcn_mfma_f32_16x16x32_f16(qhi[kc], kl, acc, 0, 0, 0);
            }
            s[ct] = acc * scale;
        }

        // online softmax
        float osc[4];
        #pragma unroll
        for (int r = 0; r < 4; ++r) {
            float tm = fmaxf(fmaxf(s[0][r], s[1][r]), fmaxf(s[2][r], s[3][r]));
            #pragma unroll
            for (int off = 8; off; off >>= 1) tm = fmaxf(tm, __shfl_xor(tm, off));
            float mn = fmaxf(m[r], tm);
            float sc = __expf(m[r] - mn);
            float rs = 0.f;
            #pragma unroll
            for (int ct = 0; ct < 4; ++ct) {
                float p = __expf(s[ct][r] - mn);
                s[ct][r] = p;
                rs += p;
            }
            #pragma unroll
            for (int off = 8; off; off >>= 1) rs += __shfl_xor(rs, off);
            l[r] = l[r] * sc + rs;
            m[r] = mn;
            osc[r] = sc;
        }
        #pragma unroll
        for (int ct = 0; ct < 8; ++ct)
            #pragma unroll
            for (int r = 0; r < 4; ++r) o[ct][r] *= osc[r];

        // P -> LDS (C-layout -> A-layout)
        _Float16* ps = &Ps[wave][0];
        #pragma unroll
        for (int ct = 0; ct < 4; ++ct)
            #pragma unroll
            for (int r = 0; r < 4; ++r)
                ps[(g * 4 + r) * SPS + ct * 16 + lr] = (_Float16)s[ct][r];

        h16x8 pa[2];
        #pragma unroll
        for (int kc = 0; kc < 2; ++kc)
            pa[kc] = *(const h16x8*)(ps + lr * SPS + kc * 32 + g * 8);

        // O += P V
        #pragma unroll
        for (int ct = 0; ct < 8; ++ct) {
            #pragma unroll
            for (int kc = 0; kc < 2; ++kc) {
                h16x8 vb = *(const h16x8*)(&Vs[(ct * 16 + lr) * SVS + kc * 32 + g * 8]);
                o[ct] = __builtin_amdgcn_mfma_f32_16x16x32_f16(pa[kc], vb, o[ct], 0, 0, 0);
            }
        }
    }

    // epilogue
    #pragma unroll
    for (int ct = 0; ct < 8; ++ct)
        #pragma unroll
        for (int r = 0; r < 4; ++r) {
            size_t row = qtok + g * 4 + r;
            out[row * EMB + ct * 16 + lr] = o[ct][r] / l[r];
        }
}

extern "C" void kernel_launch(void* const* d_in, const int* in_sizes, int n_in,
                              void* d_out, int out_size, void* d_ws, size_t ws_size,
                              hipStream_t stream) {
    const float* x  = (const float*)d_in[0];
    const float* wq = (const float*)d_in[1];
    const float* wk = (const float*)d_in[2];
    const float* wv = (const float*)d_in[3];

    char* ws = (char*)d_ws;
    _Float16* q    = (_Float16*)(ws);                        // 16 MB (hi|lo)
    _Float16* kk   = (_Float16*)(ws + (size_t)16 * 1024 * 1024);   // 16 MB
    _Float16* vT   = (_Float16*)(ws + (size_t)32 * 1024 * 1024);   // 8 MB
    _Float16* whiT = (_Float16*)(ws + (size_t)40 * 1024 * 1024);   // 96 KB
    _Float16* wloT = (_Float16*)(ws + (size_t)40 * 1024 * 1024 + 98304);

    prep_w<<<192, 256, 0, stream>>>(wq, wk, wv, whiT, wloT);
    qkv_proj<<<512, 256, 0, stream>>>(x, whiT, wloT, q, kk, vT);
    flash<<<512, 256, 0, stream>>>(q, kk, vT, (float*)d_out);
}